// Round 4
// baseline (149.792 us; speedup 1.0000x reference)
//
#include <hip/hip_runtime.h>

typedef float  f32x4  __attribute__((ext_vector_type(4)));
typedef short  s16x8  __attribute__((ext_vector_type(8)));
typedef short  s16x4  __attribute__((ext_vector_type(4)));

__device__ __forceinline__ unsigned short f2bf(float f) {
    unsigned int u = __float_as_uint(f);
    return (unsigned short)((u + 0x7FFFu + ((u >> 16) & 1u)) >> 16);
}

// pack 8 f32 -> 8 bf16 via 4x v_cvt_pk_bf16_f32 (RNE)
__device__ __forceinline__ s16x8 cvt8(f32x4 a, f32x4 b) {
    union { unsigned int u[4]; s16x8 v; } r;
    asm("v_cvt_pk_bf16_f32 %0, %1, %2" : "=v"(r.u[0]) : "v"(a[0]), "v"(a[1]));
    asm("v_cvt_pk_bf16_f32 %0, %1, %2" : "=v"(r.u[1]) : "v"(a[2]), "v"(a[3]));
    asm("v_cvt_pk_bf16_f32 %0, %1, %2" : "=v"(r.u[2]) : "v"(b[0]), "v"(b[1]));
    asm("v_cvt_pk_bf16_f32 %0, %1, %2" : "=v"(r.u[3]) : "v"(b[2]), "v"(b[3]));
    return r.v;
}

// ---------------------------------------------------------------------------
// Kernel 0: build Wt bf16 [384][1024]: Wt[n][k] = W_sel[k][n&127]
// ---------------------------------------------------------------------------
__global__ void prep_wt(const float* __restrict__ Wq,
                        const float* __restrict__ Wk,
                        const float* __restrict__ Wv,
                        unsigned short* __restrict__ wt) {
    int n = blockIdx.x;                       // 0..383
    const float* W = (n < 128) ? Wq : ((n < 256) ? Wk : Wv);
    int h = n & 127;
    for (int k = threadIdx.x; k < 1024; k += blockDim.x) {
        wt[(size_t)n * 1024 + k] = f2bf(W[(size_t)k * 128 + h]);
    }
}

// ---------------------------------------------------------------------------
// Kernel 1: QKV GEMM — ZERO LDS, ZERO BARRIERS.
// Each wave owns a 64x96 output tile (acc 4x6 frags).  A fragments are read
// DIRECTLY from x (f32, 2x f32x4 per frag) and converted with
// v_cvt_pk_bf16_f32; B fragments directly from L2-resident wt (16B/lane IS
// the fragment).  Depth-1 software pipeline: loads for step k+1 issued
// before step k's MFMAs, counted vmcnt only (never drained — no barriers).
// 8 waves = 2M x 4N -> block tile 128x384; grid 256 = 1 block/CU; x read
// exactly once.
// Outputs: Q,K bf16 [B*T][128]; V transposed bf16 [B][128][256].
// ---------------------------------------------------------------------------
__global__ __launch_bounds__(512, 2) void qkv_gemm(
    const float* __restrict__ x,
    const unsigned short* __restrict__ wt,
    unsigned short* __restrict__ qo,
    unsigned short* __restrict__ ko,
    unsigned short* __restrict__ vto) {

    const int tid = threadIdx.x;
    const int bm  = blockIdx.x;               // 0..255 (M tiles of 128)
    const int lane = tid & 63, wid = tid >> 6;
    const int lm = lane & 15, l4 = lane >> 4;
    const int wm = wid >> 2, wn = wid & 3;    // 2 (M) x 4 (N) waves

    f32x4 acc[4][6];
#pragma unroll
    for (int i = 0; i < 4; ++i)
#pragma unroll
        for (int j = 0; j < 6; ++j) acc[i][j] = (f32x4)0.f;

    // A: frag mi, step kk -> x[(bm*128 + wm*64 + mi*16 + lm)*1024 + kk*32 + l4*8 + j]
    const float* xr = x + (size_t)(bm * 128 + wm * 64 + lm) * 1024 + l4 * 8;
    // B: frag ni, step kk -> wt[(wn*96 + ni*16 + lm)*1024 + kk*32 + l4*8 + j]
    const unsigned short* wb = wt + (size_t)(wn * 96 + lm) * 1024 + l4 * 8;

    // ---- prologue: A(0), B(0) in flight ----
    f32x4 pa[8];
    s16x8 pbA[6], pbB[6];
#pragma unroll
    for (int mi = 0; mi < 4; ++mi) {
        pa[mi * 2]     = *(const f32x4*)(xr + mi * 16384);
        pa[mi * 2 + 1] = *(const f32x4*)(xr + mi * 16384 + 4);
    }
#pragma unroll
    for (int ni = 0; ni < 6; ++ni)
        pbA[ni] = *(const s16x8*)(wb + ni * 16384);

    for (int kk = 0; kk < 32; kk += 2) {
        // ======== even step: consume pa=A(kk), pbA=B(kk) ========
        s16x8 ca[4];
#pragma unroll
        for (int mi = 0; mi < 4; ++mi) ca[mi] = cvt8(pa[mi * 2], pa[mi * 2 + 1]);
        // issue A(kk+1), B(kk+1)  (kk+1 <= 31 always)
#pragma unroll
        for (int mi = 0; mi < 4; ++mi) {
            pa[mi * 2]     = *(const f32x4*)(xr + mi * 16384 + (kk + 1) * 32);
            pa[mi * 2 + 1] = *(const f32x4*)(xr + mi * 16384 + (kk + 1) * 32 + 4);
        }
#pragma unroll
        for (int ni = 0; ni < 6; ++ni)
            pbB[ni] = *(const s16x8*)(wb + ni * 16384 + (kk + 1) * 32);
#pragma unroll
        for (int ni = 0; ni < 6; ++ni)
#pragma unroll
            for (int mi = 0; mi < 4; ++mi)
                acc[mi][ni] = __builtin_amdgcn_mfma_f32_16x16x32_bf16(
                    ca[mi], pbA[ni], acc[mi][ni], 0, 0, 0);

        // ======== odd step: consume pa=A(kk+1), pbB=B(kk+1) ========
#pragma unroll
        for (int mi = 0; mi < 4; ++mi) ca[mi] = cvt8(pa[mi * 2], pa[mi * 2 + 1]);
        if (kk + 2 < 32) {
#pragma unroll
            for (int mi = 0; mi < 4; ++mi) {
                pa[mi * 2]     = *(const f32x4*)(xr + mi * 16384 + (kk + 2) * 32);
                pa[mi * 2 + 1] = *(const f32x4*)(xr + mi * 16384 + (kk + 2) * 32 + 4);
            }
#pragma unroll
            for (int ni = 0; ni < 6; ++ni)
                pbA[ni] = *(const s16x8*)(wb + ni * 16384 + (kk + 2) * 32);
        }
#pragma unroll
        for (int ni = 0; ni < 6; ++ni)
#pragma unroll
            for (int mi = 0; mi < 4; ++mi)
                acc[mi][ni] = __builtin_amdgcn_mfma_f32_16x16x32_bf16(
                    ca[mi], pbB[ni], acc[mi][ni], 0, 0, 0);
    }

    // ---- epilogue ----
#pragma unroll
    for (int mi = 0; mi < 4; ++mi) {
        int m0 = bm * 128 + wm * 64 + mi * 16 + l4 * 4;   // global row (j adds 0..3)
#pragma unroll
        for (int ni = 0; ni < 6; ++ni) {
            int nb  = wn * 96 + ni * 16;
            int mat = nb >> 7;                 // 0=Q 1=K 2=V
            int col = (nb & 127) + lm;
            if (mat == 2) {
                int bb = m0 >> 8, t = m0 & 255;
                s16x4 w4;
#pragma unroll
                for (int j = 0; j < 4; ++j) w4[j] = (short)f2bf(acc[mi][ni][j]);
                *(s16x4*)(vto + ((size_t)bb * 128 + col) * 256 + t) = w4;
            } else {
                unsigned short* dst = (mat == 0) ? qo : ko;
#pragma unroll
                for (int j = 0; j < 4; ++j)
                    dst[(size_t)(m0 + j) * 128 + col] = f2bf(acc[mi][ni][j]);
            }
        }
    }
}

// ---------------------------------------------------------------------------
// Kernel 2: causal attention.  2 blocks per batch (q-tiles of 128 rows),
// 8 waves x 16 q-rows.  Swapped QK^T (S^T = mfma(K,Q)) so softmax reduction
// is 2 shfl_xor; P packed to swizzled LDS; PV swapped (out^T = mfma(V^T,P^T))
// giving contiguous float4 output stores.
// ---------------------------------------------------------------------------
__global__ __launch_bounds__(512) void attn(
    const unsigned short* __restrict__ q,
    const unsigned short* __restrict__ k,
    const unsigned short* __restrict__ vt,
    float* __restrict__ out) {

    __shared__ char pbuf[65536];               // 8 waves x [16][256] bf16

    const int tid = threadIdx.x, wid = tid >> 6, lane = tid & 63;
    const int lm = lane & 15, l4 = lane >> 4;
    const int b = blockIdx.x >> 1, qt = blockIdx.x & 1;
    const int qbase = qt << 7;
    const int t0 = qbase + wid * 16;
    const int nfrags = (qbase + 128) >> 4;     // 8 or 16 (kv 16-frags)
    const int nkf    = (qbase + 128) >> 5;     // 4 or 8  (kv 32-frags)

    // Q fragments (B-operand: col = t = lm, 8 contiguous h per lane)
    const unsigned short* qrow = q + (size_t)(b * 256 + t0 + lm) * 128 + l4 * 8;
    s16x8 qf[4];
#pragma unroll
    for (int kf = 0; kf < 4; ++kf) qf[kf] = *(const s16x8*)(qrow + kf * 32);

    // S^T accumulators: col = t (lm), row = kv = nf*16 + l4*4 + j
    f32x4 sacc[16];
#pragma unroll
    for (int i = 0; i < 16; ++i) sacc[i] = (f32x4)0.f;

    const unsigned short* kbase = k + (size_t)(b * 256) * 128 + l4 * 8;
#pragma unroll
    for (int nf = 0; nf < 16; ++nf) {
        if (nf < nfrags) {
#pragma unroll
            for (int kf = 0; kf < 4; ++kf) {
                s16x8 a = *(const s16x8*)(kbase + (size_t)(nf * 16 + lm) * 128 + kf * 32);
                sacc[nf] = __builtin_amdgcn_mfma_f32_16x16x32_bf16(a, qf[kf], sacc[nf], 0, 0, 0);
            }
        }
    }

    // ---- mask + scale + softmax (per column t = t0+lm) ----
    const float scale = 0.08838834764831845f;  // 1/sqrt(128)
    const int tg = t0 + lm;
    float mx = -1e30f;
#pragma unroll
    for (int nf = 0; nf < 16; ++nf) {
        if (nf < nfrags) {
#pragma unroll
            for (int j = 0; j < 4; ++j) {
                int kv = nf * 16 + l4 * 4 + j;
                float s = sacc[nf][j] * scale;
                s = (kv > tg) ? -1e30f : s;
                sacc[nf][j] = s;
                mx = fmaxf(mx, s);
            }
        }
    }
    mx = fmaxf(mx, __shfl_xor(mx, 16));
    mx = fmaxf(mx, __shfl_xor(mx, 32));
    float sum = 0.f;
#pragma unroll
    for (int nf = 0; nf < 16; ++nf) {
        if (nf < nfrags) {
#pragma unroll
            for (int j = 0; j < 4; ++j) {
                float p = __expf(sacc[nf][j] - mx);
                sacc[nf][j] = p;
                sum += p;
            }
        }
    }
    sum += __shfl_xor(sum, 16);
    sum += __shfl_xor(sum, 32);
    float rinv = 1.0f / sum;

    // ---- pack P to LDS: layout [t=16][kv=256] bf16, XOR-swizzled ----
    char* pw = pbuf + wid * 8192 + lm * 512;
#pragma unroll
    for (int nf = 0; nf < 16; ++nf) {
        if (nf < nfrags) {
            s16x4 w;
#pragma unroll
            for (int j = 0; j < 4; ++j) w[j] = (short)f2bf(sacc[nf][j] * rinv);
            *(s16x4*)(pw + ((nf * 32 + l4 * 8) ^ ((lm & 7) << 4))) = w;
        }
    }
    asm volatile("s_waitcnt lgkmcnt(0)" ::: "memory");

    // ---- PV: out^T = V^T (A) x P^T (B) ----
    f32x4 oacc[8];
#pragma unroll
    for (int i = 0; i < 8; ++i) oacc[i] = (f32x4)0.f;

    const unsigned short* vbase = vt + (size_t)b * 32768 + l4 * 8;
#pragma unroll
    for (int kvf = 0; kvf < 8; ++kvf) {
        if (kvf < nkf) {
            s16x8 pf = *(const s16x8*)(pbuf + wid * 8192 + lm * 512 +
                        ((kvf * 64 + l4 * 16) ^ ((lm & 7) << 4)));
#pragma unroll
            for (int hf = 0; hf < 8; ++hf) {
                s16x8 a = *(const s16x8*)(vbase + (size_t)(hf * 16 + lm) * 256 + kvf * 32);
                oacc[hf] = __builtin_amdgcn_mfma_f32_16x16x32_bf16(a, pf, oacc[hf], 0, 0, 0);
            }
        }
    }

    // ---- store out[b][t][h] f32, contiguous float4 per lane ----
    float* ob = out + (size_t)(b * 256 + t0 + lm) * 128 + l4 * 4;
#pragma unroll
    for (int hf = 0; hf < 8; ++hf)
        *(f32x4*)(ob + hf * 16) = oacc[hf];
}

// ---------------------------------------------------------------------------
extern "C" void kernel_launch(void* const* d_in, const int* in_sizes, int n_in,
                              void* d_out, int out_size, void* d_ws, size_t ws_size,
                              hipStream_t stream) {
    const float* x  = (const float*)d_in[0];
    const float* Wq = (const float*)d_in[1];
    const float* Wk = (const float*)d_in[2];
    const float* Wv = (const float*)d_in[3];
    float* out = (float*)d_out;

    char* ws = (char*)d_ws;
    unsigned short* wt = (unsigned short*)(ws);                    // 384*1024*2   = 786432
    unsigned short* qb = (unsigned short*)(ws + 786432);           // 32768*128*2  = 8388608
    unsigned short* kb = (unsigned short*)(ws + 786432 + 8388608);
    unsigned short* vb = (unsigned short*)(ws + 786432 + 2 * 8388608);

    prep_wt<<<384, 256, 0, stream>>>(Wq, Wk, Wv, wt);
    qkv_gemm<<<256, 512, 0, stream>>>(x, wt, qb, kb, vb);
    attn<<<256, 512, 0, stream>>>(qb, kb, vb, out);
}

// Round 5
// 85.518 us; speedup vs baseline: 1.7516x; 1.7516x over previous
//
#include <hip/hip_runtime.h>

typedef float  f32x4  __attribute__((ext_vector_type(4)));
typedef short  s16x8  __attribute__((ext_vector_type(8)));
typedef short  s16x4  __attribute__((ext_vector_type(4)));

__device__ __forceinline__ unsigned short f2bf(float f) {
    unsigned int u = __float_as_uint(f);
    return (unsigned short)((u + 0x7FFFu + ((u >> 16) & 1u)) >> 16);
}

// pack 8 f32 -> 8 bf16 via 4x v_cvt_pk_bf16_f32 (RNE)
__device__ __forceinline__ s16x8 cvt8(f32x4 a, f32x4 b) {
    union { unsigned int u[4]; s16x8 v; } r;
    asm("v_cvt_pk_bf16_f32 %0, %1, %2" : "=v"(r.u[0]) : "v"(a[0]), "v"(a[1]));
    asm("v_cvt_pk_bf16_f32 %0, %1, %2" : "=v"(r.u[1]) : "v"(a[2]), "v"(a[3]));
    asm("v_cvt_pk_bf16_f32 %0, %1, %2" : "=v"(r.u[2]) : "v"(b[0]), "v"(b[1]));
    asm("v_cvt_pk_bf16_f32 %0, %1, %2" : "=v"(r.u[3]) : "v"(b[2]), "v"(b[3]));
    return r.v;
}

// barrier that does NOT drain vmcnt: only LDS ops are fenced.
__device__ __forceinline__ void lds_barrier() {
    asm volatile("s_waitcnt lgkmcnt(0)" ::: "memory");
    __builtin_amdgcn_s_barrier();
    asm volatile("" ::: "memory");
}

// ---------------------------------------------------------------------------
// Kernel 0: build Wt bf16 [384][1024]: Wt[n][k] = W_sel[k][n&127]
// ---------------------------------------------------------------------------
__global__ void prep_wt(const float* __restrict__ Wq,
                        const float* __restrict__ Wk,
                        const float* __restrict__ Wv,
                        unsigned short* __restrict__ wt) {
    int n = blockIdx.x;                       // 0..383
    const float* W = (n < 128) ? Wq : ((n < 256) ? Wk : Wv);
    int h = n & 127;
    for (int k = threadIdx.x; k < 1024; k += blockDim.x) {
        wt[(size_t)n * 1024 + k] = f2bf(W[(size_t)k * 128 + h]);
    }
}

// ---------------------------------------------------------------------------
// Kernel 1: QKV GEMM.  BM=64, BN=384 (x read exactly once), BK=64,
// 8 waves as 1M x 8N (wave = 64 rows x 48 cols, acc 4x3).
// Staging: A (f32->bf16 cvt_pk) and B (bf16) reg-staged with COALESCED
// global loads, written to a single 56KB swizzled LDS buffer.
// KEY: raw s_barrier + lgkmcnt-only waits — vmcnt is NEVER drained in the
// main loop; next-step loads issued right after the buf-ready barrier stay
// in flight across the whole compute phase and both barriers (sustained
// memory-level parallelism; the previous rounds' __syncthreads drained
// vmcnt(0) every step, collapsing MLP -> 13% HBM).
// Outputs: Q,K bf16 [B*T][128]; V transposed bf16 [B][128][256].
// ---------------------------------------------------------------------------
__global__ __launch_bounds__(512, 4) void qkv_gemm(
    const float* __restrict__ x,
    const unsigned short* __restrict__ wt,
    unsigned short* __restrict__ qo,
    unsigned short* __restrict__ ko,
    unsigned short* __restrict__ vto) {

    __shared__ char smem[57344];              // A: [0,8K) [64][128B], B: [8K,56K) [384][128B]

    const int tid = threadIdx.x;
    const int bm  = blockIdx.x;               // 0..511 (M tiles of 64)
    const int lane = tid & 63, wid = tid >> 6;
    const int lm = lane & 15, l4 = lane >> 4;

    f32x4 acc[4][3];
#pragma unroll
    for (int i = 0; i < 4; ++i)
#pragma unroll
        for (int j = 0; j < 3; ++j) acc[i][j] = (f32x4)0.f;

    // ---- A staging: thread t -> row t>>3, 8 consecutive f32 (coalesced) ----
    const int ar = tid >> 3;
    const float* xp = x + (size_t)(bm * 64 + ar) * 1024 + ((tid & 7) << 3);
    const int awr = ar * 128 + ((((tid & 7) << 4)) ^ ((ar & 7) << 4));

    // ---- B staging: 3 chunks of 16B per thread (coalesced within rows) ----
    int bgo[3], blw[3];
#pragma unroll
    for (int c = 0; c < 3; ++c) {
        int idx = c * 512 + tid;              // 0..1535
        int row = idx >> 3;                   // 0..191  (2 rows per k-half? no: 384 rows, 8 chunks/row? )
        // 384 rows x 64 bf16 = 128B/row = 8 chunks of 16B -> 3072 chunks, but
        // we have 512 threads x 3 = 1536... so 2 chunk-groups per row pass:
        // use idx over 1536 covering rows 0..191 only would be wrong.
        // Correct mapping: 3072 chunks need 6 per thread at 16B... instead use
        // 32B per thread x 3 chunks: thread covers 2 adjacent 16B chunks.
        (void)row;
        bgo[c] = 0; blw[c] = 0;               // placeholder, set below
    }
    // B tile = 384 rows x 128B = 48KB = 3072 x 16B chunks; 512 threads -> 6
    // chunks/thread. Load as 3 x 32B (s16x8 pairs? keep 16B units, 6 loads).
    int bgo6[6], blw6[6];
#pragma unroll
    for (int c = 0; c < 6; ++c) {
        int idx = c * 512 + tid;              // 0..3071
        int row = idx >> 3;                   // 0..383
        int c8  = idx & 7;                    // 16B chunk in row
        bgo6[c] = row * 1024 + c8 * 8;        // element offset (add ks*64)
        blw6[c] = 8192 + row * 128 + ((c8 * 16) ^ ((row & 7) << 4));
    }

    // ---- frag read geometry (per wave) ----
    // A frags: row = mi*16+lm ; B frags: row = wid*48 + ni*16 + lm
    int arow[4], brow[3];
#pragma unroll
    for (int mi = 0; mi < 4; ++mi) arow[mi] = mi * 16 + lm;
#pragma unroll
    for (int ni = 0; ni < 3; ++ni) brow[ni] = wid * 48 + ni * 16 + lm;

    // ---- pipeline registers + prologue issue (step 0) ----
    f32x4 pa0 = *(const f32x4*)(xp);
    f32x4 pa1 = *(const f32x4*)(xp + 4);
    s16x8 pb[6];
#pragma unroll
    for (int c = 0; c < 6; ++c) pb[c] = *(const s16x8*)(wt + bgo6[c]);

    for (int ks = 0; ks < 16; ++ks) {
        lds_barrier();                        // all waves done reading buf
        // ---- write staged regs -> LDS (compiler inserts counted vmcnt) ----
        *(s16x8*)(smem + awr) = cvt8(pa0, pa1);
#pragma unroll
        for (int c = 0; c < 6; ++c) *(s16x8*)(smem + blw6[c]) = pb[c];
        lds_barrier();                        // buf ready
        // ---- issue next step's loads: in flight across whole compute ----
        if (ks < 15) {
            pa0 = *(const f32x4*)(xp + (ks + 1) * 64);
            pa1 = *(const f32x4*)(xp + (ks + 1) * 64 + 4);
#pragma unroll
            for (int c = 0; c < 6; ++c)
                pb[c] = *(const s16x8*)(wt + bgo6[c] + (ks + 1) * 64);
        }
        // ---- compute ----
#pragma unroll
        for (int kkk = 0; kkk < 2; ++kkk) {
            s16x8 af[4], bf[3];
#pragma unroll
            for (int mi = 0; mi < 4; ++mi)
                af[mi] = *(const s16x8*)(smem + arow[mi] * 128 +
                           ((kkk * 64 + l4 * 16) ^ ((arow[mi] & 7) << 4)));
#pragma unroll
            for (int ni = 0; ni < 3; ++ni)
                bf[ni] = *(const s16x8*)(smem + 8192 + brow[ni] * 128 +
                           ((kkk * 64 + l4 * 16) ^ ((brow[ni] & 7) << 4)));
#pragma unroll
            for (int ni = 0; ni < 3; ++ni)
#pragma unroll
                for (int mi = 0; mi < 4; ++mi)
                    acc[mi][ni] = __builtin_amdgcn_mfma_f32_16x16x32_bf16(
                        af[mi], bf[ni], acc[mi][ni], 0, 0, 0);
        }
    }

    // ---- epilogue ----
#pragma unroll
    for (int mi = 0; mi < 4; ++mi) {
        int m0 = bm * 64 + mi * 16 + l4 * 4;   // global row (j adds 0..3)
#pragma unroll
        for (int ni = 0; ni < 3; ++ni) {
            int nb  = wid * 48 + ni * 16;
            int mat = nb >> 7;                 // 0=Q 1=K 2=V
            int col = (nb & 127) + lm;
            if (mat == 2) {
                int bb = m0 >> 8, t = m0 & 255;
                s16x4 w4;
#pragma unroll
                for (int j = 0; j < 4; ++j) w4[j] = (short)f2bf(acc[mi][ni][j]);
                *(s16x4*)(vto + ((size_t)bb * 128 + col) * 256 + t) = w4;
            } else {
                unsigned short* dst = (mat == 0) ? qo : ko;
#pragma unroll
                for (int j = 0; j < 4; ++j)
                    dst[(size_t)(m0 + j) * 128 + col] = f2bf(acc[mi][ni][j]);
            }
        }
    }
}

// ---------------------------------------------------------------------------
// Kernel 2: causal attention (unchanged from round 2; ~6µs).
// ---------------------------------------------------------------------------
__global__ __launch_bounds__(512) void attn(
    const unsigned short* __restrict__ q,
    const unsigned short* __restrict__ k,
    const unsigned short* __restrict__ vt,
    float* __restrict__ out) {

    __shared__ char pbuf[65536];               // 8 waves x [16][256] bf16

    const int tid = threadIdx.x, wid = tid >> 6, lane = tid & 63;
    const int lm = lane & 15, l4 = lane >> 4;
    const int b = blockIdx.x >> 1, qt = blockIdx.x & 1;
    const int qbase = qt << 7;
    const int t0 = qbase + wid * 16;
    const int nfrags = (qbase + 128) >> 4;     // 8 or 16 (kv 16-frags)
    const int nkf    = (qbase + 128) >> 5;     // 4 or 8  (kv 32-frags)

    const unsigned short* qrow = q + (size_t)(b * 256 + t0 + lm) * 128 + l4 * 8;
    s16x8 qf[4];
#pragma unroll
    for (int kf = 0; kf < 4; ++kf) qf[kf] = *(const s16x8*)(qrow + kf * 32);

    f32x4 sacc[16];
#pragma unroll
    for (int i = 0; i < 16; ++i) sacc[i] = (f32x4)0.f;

    const unsigned short* kbase = k + (size_t)(b * 256) * 128 + l4 * 8;
#pragma unroll
    for (int nf = 0; nf < 16; ++nf) {
        if (nf < nfrags) {
#pragma unroll
            for (int kf = 0; kf < 4; ++kf) {
                s16x8 a = *(const s16x8*)(kbase + (size_t)(nf * 16 + lm) * 128 + kf * 32);
                sacc[nf] = __builtin_amdgcn_mfma_f32_16x16x32_bf16(a, qf[kf], sacc[nf], 0, 0, 0);
            }
        }
    }

    const float scale = 0.08838834764831845f;  // 1/sqrt(128)
    const int tg = t0 + lm;
    float mx = -1e30f;
#pragma unroll
    for (int nf = 0; nf < 16; ++nf) {
        if (nf < nfrags) {
#pragma unroll
            for (int j = 0; j < 4; ++j) {
                int kv = nf * 16 + l4 * 4 + j;
                float s = sacc[nf][j] * scale;
                s = (kv > tg) ? -1e30f : s;
                sacc[nf][j] = s;
                mx = fmaxf(mx, s);
            }
        }
    }
    mx = fmaxf(mx, __shfl_xor(mx, 16));
    mx = fmaxf(mx, __shfl_xor(mx, 32));
    float sum = 0.f;
#pragma unroll
    for (int nf = 0; nf < 16; ++nf) {
        if (nf < nfrags) {
#pragma unroll
            for (int j = 0; j < 4; ++j) {
                float p = __expf(sacc[nf][j] - mx);
                sacc[nf][j] = p;
                sum += p;
            }
        }
    }
    sum += __shfl_xor(sum, 16);
    sum += __shfl_xor(sum, 32);
    float rinv = 1.0f / sum;

    char* pw = pbuf + wid * 8192 + lm * 512;
#pragma unroll
    for (int nf = 0; nf < 16; ++nf) {
        if (nf < nfrags) {
            s16x4 w;
#pragma unroll
            for (int j = 0; j < 4; ++j) w[j] = (short)f2bf(sacc[nf][j] * rinv);
            *(s16x4*)(pw + ((nf * 32 + l4 * 8) ^ ((lm & 7) << 4))) = w;
        }
    }
    asm volatile("s_waitcnt lgkmcnt(0)" ::: "memory");

    f32x4 oacc[8];
#pragma unroll
    for (int i = 0; i < 8; ++i) oacc[i] = (f32x4)0.f;

    const unsigned short* vbase = vt + (size_t)b * 32768 + l4 * 8;
#pragma unroll
    for (int kvf = 0; kvf < 8; ++kvf) {
        if (kvf < nkf) {
            s16x8 pf = *(const s16x8*)(pbuf + wid * 8192 + lm * 512 +
                        ((kvf * 64 + l4 * 16) ^ ((lm & 7) << 4)));
#pragma unroll
            for (int hf = 0; hf < 8; ++hf) {
                s16x8 a = *(const s16x8*)(vbase + (size_t)(hf * 16 + lm) * 256 + kvf * 32);
                oacc[hf] = __builtin_amdgcn_mfma_f32_16x16x32_bf16(a, pf, oacc[hf], 0, 0, 0);
            }
        }
    }

    float* ob = out + (size_t)(b * 256 + t0 + lm) * 128 + l4 * 4;
#pragma unroll
    for (int hf = 0; hf < 8; ++hf)
        *(f32x4*)(ob + hf * 16) = oacc[hf];
}

// ---------------------------------------------------------------------------
extern "C" void kernel_launch(void* const* d_in, const int* in_sizes, int n_in,
                              void* d_out, int out_size, void* d_ws, size_t ws_size,
                              hipStream_t stream) {
    const float* x  = (const float*)d_in[0];
    const float* Wq = (const float*)d_in[1];
    const float* Wk = (const float*)d_in[2];
    const float* Wv = (const float*)d_in[3];
    float* out = (float*)d_out;

    char* ws = (char*)d_ws;
    unsigned short* wt = (unsigned short*)(ws);                    // 384*1024*2   = 786432
    unsigned short* qb = (unsigned short*)(ws + 786432);           // 32768*128*2  = 8388608
    unsigned short* kb = (unsigned short*)(ws + 786432 + 8388608);
    unsigned short* vb = (unsigned short*)(ws + 786432 + 2 * 8388608);

    prep_wt<<<384, 256, 0, stream>>>(Wq, Wk, Wv, wt);
    qkv_gemm<<<512, 512, 0, stream>>>(x, wt, qb, kb, vb);
    attn<<<256, 512, 0, stream>>>(qb, kb, vb, out);
}

// Round 6
// 78.688 us; speedup vs baseline: 1.9036x; 1.0868x over previous
//
#include <hip/hip_runtime.h>

typedef float  f32x4  __attribute__((ext_vector_type(4)));
typedef short  s16x8  __attribute__((ext_vector_type(8)));
typedef short  s16x4  __attribute__((ext_vector_type(4)));

__device__ __forceinline__ unsigned short f2bf(float f) {
    unsigned int u = __float_as_uint(f);
    return (unsigned short)((u + 0x7FFFu + ((u >> 16) & 1u)) >> 16);
}

// pack 8 f32 -> 8 bf16 via 4x v_cvt_pk_bf16_f32 (RNE)
__device__ __forceinline__ s16x8 cvt8(f32x4 a, f32x4 b) {
    union { unsigned int u[4]; s16x8 v; } r;
    asm("v_cvt_pk_bf16_f32 %0, %1, %2" : "=v"(r.u[0]) : "v"(a[0]), "v"(a[1]));
    asm("v_cvt_pk_bf16_f32 %0, %1, %2" : "=v"(r.u[1]) : "v"(a[2]), "v"(a[3]));
    asm("v_cvt_pk_bf16_f32 %0, %1, %2" : "=v"(r.u[2]) : "v"(b[0]), "v"(b[1]));
    asm("v_cvt_pk_bf16_f32 %0, %1, %2" : "=v"(r.u[3]) : "v"(b[2]), "v"(b[3]));
    return r.v;
}

// async global->LDS, 16B per lane.  LDS dest is wave-uniform base + lane*16;
// global src is per-lane.
#define GLOAD_LDS16(g, l) __builtin_amdgcn_global_load_lds(                    \
    (const __attribute__((address_space(1))) void*)(g),                        \
    (__attribute__((address_space(3))) void*)(l), 16, 0, 0)

// ---------------------------------------------------------------------------
// Kernel 0: build wt2 = swizzle-tiled bf16 weights.
// Element (n,k), n in [0,384) (0..127=Q,128..255=K,256..383=V), k in [0,1024):
//   byte offset = (k>>6)*49152 + n*128 + ((2*(k&63)) ^ ((n&7)<<4))
// i.e. 16 K-tiles of [384 rows][128B], XOR-swizzled within each row so a
// LINEAR global_load_lds of one tile produces the bank-conflict-free LDS
// layout the MFMA fragment reads expect (inverse-swz source pattern, m173).
// ---------------------------------------------------------------------------
__global__ void prep_wt(const float* __restrict__ Wq,
                        const float* __restrict__ Wk,
                        const float* __restrict__ Wv,
                        unsigned char* __restrict__ wt2) {
    int n = blockIdx.x;                       // 0..383
    const float* W = (n < 128) ? Wq : ((n < 256) ? Wk : Wv);
    int h = n & 127;
    for (int k = threadIdx.x; k < 1024; k += blockDim.x) {
        unsigned short v = f2bf(W[(size_t)k * 128 + h]);
        size_t off = (size_t)(k >> 6) * 49152 + (size_t)n * 128 +
                     (((k & 63) * 2) ^ ((n & 7) << 4));
        *(unsigned short*)(wt2 + off) = v;
    }
}

// ---------------------------------------------------------------------------
// Kernel 1: QKV GEMM.  BM=128, BN=384 (x read exactly once), BK=64.
// Grid 256 = 1 block/CU, 8 waves as 2M x 4N (wave = 64 rows x 96 cols,
// acc 4x6).  Double-buffered LDS: A 2x16KB (reg-staged f32->bf16, swizzled)
// + B 2x48KB (staged by global_load_lds from pre-swizzled wt2 — no VGPR
// round-trip, no vmcnt-before-ds_write dependency).  ONE barrier per K-step;
// next step's A loads + B gload_lds issued at step start, A cvt+write after
// the 48-MFMA cluster (T14 issue-early/write-late: ~1800cy in flight covers
// HBM latency).  B L2 re-fetch = 48KB/CU-step (was 96).
// Outputs: Q,K bf16 [B*T][128]; V transposed bf16 [B][128][256].
// ---------------------------------------------------------------------------
__global__ __launch_bounds__(512, 2) void qkv_gemm(
    const float* __restrict__ x,
    const unsigned char* __restrict__ wt2,
    unsigned short* __restrict__ qo,
    unsigned short* __restrict__ ko,
    unsigned short* __restrict__ vto) {

    // A buffers: [0,16K) and [16K,32K).  B buffers: [32K,80K) and [80K,128K).
    __shared__ char smem[131072];

    const int tid = threadIdx.x;
    const int bm  = blockIdx.x;               // 0..255 (M tiles of 128)
    const int lane = tid & 63, wid = tid >> 6;
    const int lm = lane & 15, l4 = lane >> 4;
    const int wm = wid >> 2, wn = wid & 3;    // 2 (M) x 4 (N)

    f32x4 acc[4][6];
#pragma unroll
    for (int i = 0; i < 4; ++i)
#pragma unroll
        for (int j = 0; j < 6; ++j) acc[i][j] = (f32x4)0.f;

    // ---- A staging geometry: thread -> row tid>>2, 16 consecutive f32 ----
    const int arow = tid >> 2;                // 0..127
    const int acb  = (tid & 3) * 16;          // f32 col base: 0,16,32,48
    const float* xp = x + (size_t)(bm * 128 + arow) * 1024 + acb;
    const int aswz = (arow & 7) << 4;
    const int aw0 = arow * 128 + ((acb * 2) ^ aswz);
    const int aw1 = arow * 128 + ((acb * 2 + 16) ^ aswz);

    // ---- B staging: 48 x 1KB chunks per tile; wave wid issues chunks
    //      wid*6 .. wid*6+5 (uniform LDS dest per wave) ----
    const int ci0 = wid * 6;
    const unsigned char* wsrc = wt2 + (size_t)ci0 * 1024 + lane * 16;

    // ---- fragment read rows ----
    int amr[4], bnr[6];
#pragma unroll
    for (int mi = 0; mi < 4; ++mi) amr[mi] = wm * 64 + mi * 16 + lm;
#pragma unroll
    for (int ni = 0; ni < 6; ++ni) bnr[ni] = wn * 96 + ni * 16 + lm;

    // ---- prologue: stage step 0 ----
    {
        f32x4 a0 = *(const f32x4*)(xp);
        f32x4 a1 = *(const f32x4*)(xp + 4);
        f32x4 a2 = *(const f32x4*)(xp + 8);
        f32x4 a3 = *(const f32x4*)(xp + 12);
#pragma unroll
        for (int c = 0; c < 6; ++c)
            GLOAD_LDS16(wsrc + c * 1024, smem + 32768 + (ci0 + c) * 1024);
        *(s16x8*)(smem + aw0) = cvt8(a0, a1);
        *(s16x8*)(smem + aw1) = cvt8(a2, a3);
    }
    __syncthreads();                          // drains vmcnt: B(0) landed

    for (int ks = 0; ks < 16; ++ks) {
        const int p = ks & 1;
        const int abase = p * 16384;
        const int bbase = 32768 + p * 49152;
        // ---- issue next step's loads (in flight across the whole step) ----
        f32x4 n0, n1, n2, n3;
        if (ks < 15) {
            const float* xq = xp + (ks + 1) * 64;
            n0 = *(const f32x4*)(xq);
            n1 = *(const f32x4*)(xq + 4);
            n2 = *(const f32x4*)(xq + 8);
            n3 = *(const f32x4*)(xq + 12);
            const unsigned char* ws = wsrc + (size_t)(ks + 1) * 49152;
#pragma unroll
            for (int c = 0; c < 6; ++c)
                GLOAD_LDS16(ws + c * 1024,
                            smem + 32768 + (p ^ 1) * 49152 + (ci0 + c) * 1024);
        }
        // ---- compute: 2 x (10 ds_read + 24 MFMA) from buf p ----
#pragma unroll
        for (int kkk = 0; kkk < 2; ++kkk) {
            s16x8 af[4], bf[6];
#pragma unroll
            for (int mi = 0; mi < 4; ++mi)
                af[mi] = *(const s16x8*)(smem + abase + amr[mi] * 128 +
                           ((kkk * 64 + l4 * 16) ^ ((amr[mi] & 7) << 4)));
#pragma unroll
            for (int ni = 0; ni < 6; ++ni)
                bf[ni] = *(const s16x8*)(smem + bbase + bnr[ni] * 128 +
                           ((kkk * 64 + l4 * 16) ^ ((bnr[ni] & 7) << 4)));
            __builtin_amdgcn_s_setprio(1);
#pragma unroll
            for (int ni = 0; ni < 6; ++ni)
#pragma unroll
                for (int mi = 0; mi < 4; ++mi)
                    acc[mi][ni] = __builtin_amdgcn_mfma_f32_16x16x32_bf16(
                        af[mi], bf[ni], acc[mi][ni], 0, 0, 0);
            __builtin_amdgcn_s_setprio(0);
        }
        // ---- stage A(ks+1) late (loads have been in flight all step) ----
        if (ks < 15) {
            *(s16x8*)(smem + (abase ^ 16384) + aw0) = cvt8(n0, n1);
            *(s16x8*)(smem + (abase ^ 16384) + aw1) = cvt8(n2, n3);
        }
        __syncthreads();                      // also drains B(ks+1) gload_lds
    }

    // ---- epilogue ----
#pragma unroll
    for (int mi = 0; mi < 4; ++mi) {
        int m0 = bm * 128 + wm * 64 + mi * 16 + l4 * 4;   // j adds 0..3
#pragma unroll
        for (int ni = 0; ni < 6; ++ni) {
            int nb  = wn * 96 + ni * 16;
            int mat = nb >> 7;                 // 0=Q 1=K 2=V
            int col = (nb & 127) + lm;
            if (mat == 2) {
                int bb = m0 >> 8, t = m0 & 255;
                s16x4 w4;
#pragma unroll
                for (int j = 0; j < 4; ++j) w4[j] = (short)f2bf(acc[mi][ni][j]);
                *(s16x4*)(vto + ((size_t)bb * 128 + col) * 256 + t) = w4;
            } else {
                unsigned short* dst = (mat == 0) ? qo : ko;
#pragma unroll
                for (int j = 0; j < 4; ++j)
                    dst[(size_t)(m0 + j) * 128 + col] = f2bf(acc[mi][ni][j]);
            }
        }
    }
}

// ---------------------------------------------------------------------------
// Kernel 2: causal attention (unchanged; ~6µs).
// ---------------------------------------------------------------------------
__global__ __launch_bounds__(512) void attn(
    const unsigned short* __restrict__ q,
    const unsigned short* __restrict__ k,
    const unsigned short* __restrict__ vt,
    float* __restrict__ out) {

    __shared__ char pbuf[65536];               // 8 waves x [16][256] bf16

    const int tid = threadIdx.x, wid = tid >> 6, lane = tid & 63;
    const int lm = lane & 15, l4 = lane >> 4;
    const int b = blockIdx.x >> 1, qt = blockIdx.x & 1;
    const int qbase = qt << 7;
    const int t0 = qbase + wid * 16;
    const int nfrags = (qbase + 128) >> 4;     // 8 or 16 (kv 16-frags)
    const int nkf    = (qbase + 128) >> 5;     // 4 or 8  (kv 32-frags)

    const unsigned short* qrow = q + (size_t)(b * 256 + t0 + lm) * 128 + l4 * 8;
    s16x8 qf[4];
#pragma unroll
    for (int kf = 0; kf < 4; ++kf) qf[kf] = *(const s16x8*)(qrow + kf * 32);

    f32x4 sacc[16];
#pragma unroll
    for (int i = 0; i < 16; ++i) sacc[i] = (f32x4)0.f;

    const unsigned short* kbase = k + (size_t)(b * 256) * 128 + l4 * 8;
#pragma unroll
    for (int nf = 0; nf < 16; ++nf) {
        if (nf < nfrags) {
#pragma unroll
            for (int kf = 0; kf < 4; ++kf) {
                s16x8 a = *(const s16x8*)(kbase + (size_t)(nf * 16 + lm) * 128 + kf * 32);
                sacc[nf] = __builtin_amdgcn_mfma_f32_16x16x32_bf16(a, qf[kf], sacc[nf], 0, 0, 0);
            }
        }
    }

    const float scale = 0.08838834764831845f;  // 1/sqrt(128)
    const int tg = t0 + lm;
    float mx = -1e30f;
#pragma unroll
    for (int nf = 0; nf < 16; ++nf) {
        if (nf < nfrags) {
#pragma unroll
            for (int j = 0; j < 4; ++j) {
                int kv = nf * 16 + l4 * 4 + j;
                float s = sacc[nf][j] * scale;
                s = (kv > tg) ? -1e30f : s;
                sacc[nf][j] = s;
                mx = fmaxf(mx, s);
            }
        }
    }
    mx = fmaxf(mx, __shfl_xor(mx, 16));
    mx = fmaxf(mx, __shfl_xor(mx, 32));
    float sum = 0.f;
#pragma unroll
    for (int nf = 0; nf < 16; ++nf) {
        if (nf < nfrags) {
#pragma unroll
            for (int j = 0; j < 4; ++j) {
                float p = __expf(sacc[nf][j] - mx);
                sacc[nf][j] = p;
                sum += p;
            }
        }
    }
    sum += __shfl_xor(sum, 16);
    sum += __shfl_xor(sum, 32);
    float rinv = 1.0f / sum;

    char* pw = pbuf + wid * 8192 + lm * 512;
#pragma unroll
    for (int nf = 0; nf < 16; ++nf) {
        if (nf < nfrags) {
            s16x4 w;
#pragma unroll
            for (int j = 0; j < 4; ++j) w[j] = (short)f2bf(sacc[nf][j] * rinv);
            *(s16x4*)(pw + ((nf * 32 + l4 * 8) ^ ((lm & 7) << 4))) = w;
        }
    }
    asm volatile("s_waitcnt lgkmcnt(0)" ::: "memory");

    f32x4 oacc[8];
#pragma unroll
    for (int i = 0; i < 8; ++i) oacc[i] = (f32x4)0.f;

    const unsigned short* vbase = vt + (size_t)b * 32768 + l4 * 8;
#pragma unroll
    for (int kvf = 0; kvf < 8; ++kvf) {
        if (kvf < nkf) {
            s16x8 pf = *(const s16x8*)(pbuf + wid * 8192 + lm * 512 +
                        ((kvf * 64 + l4 * 16) ^ ((lm & 7) << 4)));
#pragma unroll
            for (int hf = 0; hf < 8; ++hf) {
                s16x8 a = *(const s16x8*)(vbase + (size_t)(hf * 16 + lm) * 256 + kvf * 32);
                oacc[hf] = __builtin_amdgcn_mfma_f32_16x16x32_bf16(a, pf, oacc[hf], 0, 0, 0);
            }
        }
    }

    float* ob = out + (size_t)(b * 256 + t0 + lm) * 128 + l4 * 4;
#pragma unroll
    for (int hf = 0; hf < 8; ++hf)
        *(f32x4*)(ob + hf * 16) = oacc[hf];
}

// ---------------------------------------------------------------------------
extern "C" void kernel_launch(void* const* d_in, const int* in_sizes, int n_in,
                              void* d_out, int out_size, void* d_ws, size_t ws_size,
                              hipStream_t stream) {
    const float* x  = (const float*)d_in[0];
    const float* Wq = (const float*)d_in[1];
    const float* Wk = (const float*)d_in[2];
    const float* Wv = (const float*)d_in[3];
    float* out = (float*)d_out;

    char* ws = (char*)d_ws;
    unsigned char*  wt = (unsigned char*)(ws);                     // 786432 B (swizzle-tiled)
    unsigned short* qb = (unsigned short*)(ws + 786432);           // 32768*128*2
    unsigned short* kb = (unsigned short*)(ws + 786432 + 8388608);
    unsigned short* vb = (unsigned short*)(ws + 786432 + 2 * 8388608);

    prep_wt<<<384, 256, 0, stream>>>(Wq, Wk, Wv, wt);
    qkv_gemm<<<256, 512, 0, stream>>>(x, wt, qb, kb, vb);
    attn<<<256, 512, 0, stream>>>(qb, kb, vb, out);
}